// Round 1
// baseline (3046.239 us; speedup 1.0000x reference)
//
#include <hip/hip_runtime.h>
#include <math.h>

#define N_TOK 4096
#define DIM   512
#define HID   2048
#define NEXP  8
#define NC    7
#define OUT_MIXED (N_TOK*DIM)   // 2097152; then [lb, ent], then sel_expert[N,2]
#define TM    16                // tokens per MLP block

// ---------------------------------------------------------------------------
// ws layout:
//   [0,32)                       int   counts[8]
//   [32,64)                      float imp_sum[8]
//   [64, 64+8*4096*4)            int   tok_list[8][4096]
//   [.., +8*4096*4)              float wt_list[8][4096]
// ---------------------------------------------------------------------------

__global__ __launch_bounds__(256) void router_kernel(
    const float* __restrict__ x, const float* __restrict__ rW,
    const float* __restrict__ rb, float* __restrict__ out,
    int* __restrict__ counts, float* __restrict__ imp_sum,
    int* __restrict__ tok_list, float* __restrict__ wt_list)
{
  __shared__ float imp_loc[8];
  const int tid = threadIdx.x;
  if (tid < 8) imp_loc[tid] = 0.f;
  __syncthreads();
  const int wave = tid >> 6, lane = tid & 63;

  for (int it = 0; it < 16; ++it) {
    const int t = blockIdx.x * 64 + wave * 16 + it;
    // each wave computes one token's 7 logits
    float xv[8];
#pragma unroll
    for (int j = 0; j < 8; ++j) xv[j] = x[(size_t)t*DIM + lane + 64*j];
    float lg[NC];
#pragma unroll
    for (int e = 0; e < NC; ++e) {
      float s = 0.f;
#pragma unroll
      for (int j = 0; j < 8; ++j) s += xv[j] * rW[(lane + 64*j)*NC + e];
      lg[e] = s;
    }
#pragma unroll
    for (int e = 0; e < NC; ++e) {
      float s = lg[e];
#pragma unroll
      for (int off = 32; off > 0; off >>= 1) s += __shfl_xor(s, off, 64);
      lg[e] = s + rb[e];
    }
    // stable top-2: strict '>' scanning ascending index == jax.lax.top_k tie-break
    int i1 = 0; float l1 = lg[0];
#pragma unroll
    for (int e = 1; e < NC; ++e) { if (lg[e] > l1) { l1 = lg[e]; i1 = e; } }
    int i2 = -1; float l2 = -3.4e38f;
#pragma unroll
    for (int e = 0; e < NC; ++e) { if (e != i1 && lg[e] > l2) { l2 = lg[e]; i2 = e; } }

    const float ed = expf(l2 - l1);
    const float g1 = 1.f/(1.f+ed), g2 = ed/(1.f+ed);

    // full softmax over 7 for importance
    float p[NC]; float ssum = 0.f;
#pragma unroll
    for (int e = 0; e < NC; ++e) { p[e] = expf(lg[e] - l1); ssum += p[e]; }
    const float inv = 1.f/ssum;

    if (lane == 0) {
#pragma unroll
      for (int e = 0; e < NC; ++e) atomicAdd(&imp_loc[e], p[e]*inv);
      out[OUT_MIXED + 2 + 2*t]     = (float)(i1 + 1);
      out[OUT_MIXED + 2 + 2*t + 1] = (float)(i2 + 1);
      const int e1 = i1 + 1, e2 = i2 + 1;
      int p1 = atomicAdd(&counts[e1], 1);
      tok_list[e1*N_TOK + p1] = t;
      wt_list [e1*N_TOK + p1] = (2.f/3.f)*g1;
      int p2 = atomicAdd(&counts[e2], 1);
      tok_list[e2*N_TOK + p2] = t;
      wt_list [e2*N_TOK + p2] = (2.f/3.f)*g2;
    }
  }
  __syncthreads();
  if (tid < NC) atomicAdd(&imp_sum[tid], imp_loc[tid]);
}

__global__ void finalize_kernel(const float* __restrict__ imp_sum,
                                float* __restrict__ out)
{
  if (threadIdx.x == 0 && blockIdx.x == 0) {
    float lb = 0.f, ent = 0.f;
    for (int e = 0; e < NC; ++e) {
      float p = imp_sum[e] * (1.f/(float)N_TOK);
      float d = p - (1.f/(float)NC);
      lb += d*d;
      ent -= p * logf(fmaxf(p, 1e-8f));
    }
    out[OUT_MIXED]     = lb * (1.f/(float)NC);
    out[OUT_MIXED + 1] = ent;
  }
}

// Grouped sparse MLP: block = (expert e, tile of TM tokens from e's list).
// xs: x-tile transposed [d][m] (+1 pad). hs: hidden chunk [k][m] (+1 pad).
// Per thread: r = tid&63, m0 = (tid>>6)*4; owns 4 tokens x 8 output dims.
__global__ __launch_bounds__(256) void moe_mlp_kernel(
    const float* __restrict__ x,
    const float* __restrict__ W1, const float* __restrict__ b1,
    const float* __restrict__ W2, const float* __restrict__ b2,
    const float* __restrict__ fixed_w,
    const int* __restrict__ counts, const int* __restrict__ tok_list,
    const float* __restrict__ wt_list, float* __restrict__ out)
{
  const int e    = blockIdx.x >> 8;     // 256 tiles per expert
  const int tile = blockIdx.x & 255;
  const int cnt  = (e == 0) ? N_TOK : counts[e];
  const int start = tile * TM;
  if (start >= cnt) return;             // uniform across block (before barriers)

  __shared__ float xs[DIM][TM+1];       // 34816 B
  __shared__ float hs[256][TM+1];       // 17408 B
  __shared__ int   tok_s[TM];
  __shared__ float wt_s[TM];

  const int tid = threadIdx.x;
  if (tid < TM) {
    int idx = start + tid; int t = 0; float w = 0.f;
    if (idx < cnt) {
      if (e == 0) { t = idx; w = (1.f/3.f) * fixed_w[0]; }
      else        { t = tok_list[e*N_TOK + idx]; w = wt_list[e*N_TOK + idx]; }
    }
    tok_s[tid] = t; wt_s[tid] = w;
  }
  __syncthreads();

  for (int i = tid; i < TM*DIM; i += 256) {
    const int m = i >> 9, d = i & (DIM-1);
    xs[d][m] = x[(size_t)tok_s[m]*DIM + d];
  }

  const int r  = tid & 63;
  const int m0 = (tid >> 6) * 4;
  const float* W1e = W1 + (size_t)e * DIM * HID;
  const float* W2e = W2 + (size_t)e * HID * DIM;
  const float* b1e = b1 + e * HID;

  float yacc[4][8];
#pragma unroll
  for (int j = 0; j < 4; ++j)
#pragma unroll
    for (int i = 0; i < 8; ++i) yacc[j][i] = 0.f;

  __syncthreads();   // xs ready

  for (int c = 0; c < 8; ++c) {
    const int k0 = c * 256;
    // ---- phase 1: hs[k][m] = relu(b1 + x @ W1[:, k0+k]), k in [0,256)
    float bv[4];
#pragma unroll
    for (int i = 0; i < 4; ++i) bv[i] = b1e[k0 + r + 64*i];
    float hacc[4][4];
#pragma unroll
    for (int j = 0; j < 4; ++j)
#pragma unroll
      for (int i = 0; i < 4; ++i) hacc[j][i] = bv[i];
#pragma unroll 2
    for (int d = 0; d < DIM; ++d) {
      float wv[4];
#pragma unroll
      for (int i = 0; i < 4; ++i) wv[i] = W1e[(size_t)d*HID + k0 + r + 64*i];
      float xv[4];
#pragma unroll
      for (int j = 0; j < 4; ++j) xv[j] = xs[d][m0+j];
#pragma unroll
      for (int j = 0; j < 4; ++j)
#pragma unroll
        for (int i = 0; i < 4; ++i) hacc[j][i] += xv[j]*wv[i];
    }
#pragma unroll
    for (int i = 0; i < 4; ++i)
#pragma unroll
      for (int j = 0; j < 4; ++j) hs[r + 64*i][m0+j] = fmaxf(hacc[j][i], 0.f);
    __syncthreads();

    // ---- phase 2: yacc += hs @ W2[k0:k0+256, :]
#pragma unroll 2
    for (int k = 0; k < 256; ++k) {
      float wv2[8];
#pragma unroll
      for (int i = 0; i < 8; ++i) wv2[i] = W2e[(size_t)(k0+k)*DIM + r + 64*i];
      float hv[4];
#pragma unroll
      for (int j = 0; j < 4; ++j) hv[j] = hs[k][m0+j];
#pragma unroll
      for (int j = 0; j < 4; ++j)
#pragma unroll
        for (int i = 0; i < 8; ++i) yacc[j][i] += hv[j]*wv2[i];
    }
    __syncthreads();
  }

  // ---- epilogue: out[t] += w * (y + b2[e])
#pragma unroll
  for (int i = 0; i < 8; ++i) {
    const int d = r + 64*i;
    const float b2v = b2[e*DIM + d];
#pragma unroll
    for (int j = 0; j < 4; ++j) {
      const int m = m0 + j;
      atomicAdd(&out[(size_t)tok_s[m]*DIM + d], wt_s[m]*(yacc[j][i] + b2v));
    }
  }
}

extern "C" void kernel_launch(void* const* d_in, const int* in_sizes, int n_in,
                              void* d_out, int out_size, void* d_ws, size_t ws_size,
                              hipStream_t stream)
{
  const float* x  = (const float*)d_in[0];
  const float* rW = (const float*)d_in[1];
  const float* rb = (const float*)d_in[2];
  const float* W1 = (const float*)d_in[3];
  const float* b1 = (const float*)d_in[4];
  const float* W2 = (const float*)d_in[5];
  const float* b2 = (const float*)d_in[6];
  const float* fw = (const float*)d_in[7];
  float* out = (float*)d_out;

  int*   counts   = (int*)d_ws;
  float* imp_sum  = (float*)((char*)d_ws + 32);
  int*   tok_list = (int*)((char*)d_ws + 64);
  float* wt_list  = (float*)((char*)d_ws + 64 + (size_t)NEXP*N_TOK*4);

  hipMemsetAsync(d_ws, 0, 64, stream);                       // counts + imp_sum
  hipMemsetAsync(d_out, 0, (size_t)OUT_MIXED*4, stream);     // mixed accumulator

  router_kernel<<<64, 256, 0, stream>>>(x, rW, rb, out, counts, imp_sum,
                                        tok_list, wt_list);
  finalize_kernel<<<1, 64, 0, stream>>>(imp_sum, out);
  moe_mlp_kernel<<<NEXP*256, 256, 0, stream>>>(x, W1, b1, W2, b2, fw,
                                               counts, tok_list, wt_list, out);
}

// Round 2
// 770.091 us; speedup vs baseline: 3.9557x; 3.9557x over previous
//
#include <hip/hip_runtime.h>
#include <math.h>

#define N_TOK 4096
#define DIM   512
#define HID   2048
#define NEXP  8
#define NC    7
#define OUT_MIXED (N_TOK*DIM)   // then [lb, ent], then sel_expert[N,2]
#define TM    16                // tokens per MLP block

typedef __attribute__((ext_vector_type(8))) short bf16x8;
typedef __attribute__((ext_vector_type(4))) float f32x4;

#define XSP 520   // xs row stride (elems): 1040B -> rows alias every 8 -> 2-way (free)
#define HSP 264   // hs row stride (elems): 528B  -> same property

// ws layout:
//   [0,32)    int counts[8]
//   [32,64)   float imp_sum[8]
//   [64,  +8*4096*4)   int   tok_list[8][4096]
//   [...  +8*4096*4)   float wt_list[8][4096]
//   262208: xbf  [4096][512] bf16                    (4 MB)
//   : W1s  [8][128 ntile][64 kblk][16 n][8 k] bf16   (16 MB)
//   : W2s  [8][32 ntile][256 kblk][16 n][8 k] bf16   (16 MB)
#define OFF_XBF  262208ull
#define OFF_W1S  (OFF_XBF + 4194304ull)
#define OFF_W2S  (OFF_W1S + 16777216ull)
#define WS_REQ   (OFF_W2S + 16777216ull)

__device__ inline unsigned short f2bf(float f) {
  unsigned int u = __builtin_bit_cast(unsigned int, f);
  u = (u + 0x7fffu + ((u >> 16) & 1u)) >> 16;   // RNE
  return (unsigned short)u;
}

// ---------------------------------------------------------------------------
// Router (fp32, unchanged from R1 — sel_expert must be bit-exact)
// ---------------------------------------------------------------------------
__global__ __launch_bounds__(256) void router_kernel(
    const float* __restrict__ x, const float* __restrict__ rW,
    const float* __restrict__ rb, float* __restrict__ out,
    int* __restrict__ counts, float* __restrict__ imp_sum,
    int* __restrict__ tok_list, float* __restrict__ wt_list)
{
  __shared__ float imp_loc[8];
  const int tid = threadIdx.x;
  if (tid < 8) imp_loc[tid] = 0.f;
  __syncthreads();
  const int wave = tid >> 6, lane = tid & 63;

  for (int it = 0; it < 16; ++it) {
    const int t = blockIdx.x * 64 + wave * 16 + it;
    float xv[8];
#pragma unroll
    for (int j = 0; j < 8; ++j) xv[j] = x[(size_t)t*DIM + lane + 64*j];
    float lg[NC];
#pragma unroll
    for (int e = 0; e < NC; ++e) {
      float s = 0.f;
#pragma unroll
      for (int j = 0; j < 8; ++j) s += xv[j] * rW[(lane + 64*j)*NC + e];
      lg[e] = s;
    }
#pragma unroll
    for (int e = 0; e < NC; ++e) {
      float s = lg[e];
#pragma unroll
      for (int off = 32; off > 0; off >>= 1) s += __shfl_xor(s, off, 64);
      lg[e] = s + rb[e];
    }
    int i1 = 0; float l1 = lg[0];
#pragma unroll
    for (int e = 1; e < NC; ++e) { if (lg[e] > l1) { l1 = lg[e]; i1 = e; } }
    int i2 = -1; float l2 = -3.4e38f;
#pragma unroll
    for (int e = 0; e < NC; ++e) { if (e != i1 && lg[e] > l2) { l2 = lg[e]; i2 = e; } }

    const float ed = expf(l2 - l1);
    const float g1 = 1.f/(1.f+ed), g2 = ed/(1.f+ed);

    float p[NC]; float ssum = 0.f;
#pragma unroll
    for (int e = 0; e < NC; ++e) { p[e] = expf(lg[e] - l1); ssum += p[e]; }
    const float inv = 1.f/ssum;

    if (lane == 0) {
#pragma unroll
      for (int e = 0; e < NC; ++e) atomicAdd(&imp_loc[e], p[e]*inv);
      out[OUT_MIXED + 2 + 2*t]     = (float)(i1 + 1);
      out[OUT_MIXED + 2 + 2*t + 1] = (float)(i2 + 1);
      const int e1 = i1 + 1, e2 = i2 + 1;
      int p1 = atomicAdd(&counts[e1], 1);
      tok_list[e1*N_TOK + p1] = t;
      wt_list [e1*N_TOK + p1] = (2.f/3.f)*g1;
      int p2 = atomicAdd(&counts[e2], 1);
      tok_list[e2*N_TOK + p2] = t;
      wt_list [e2*N_TOK + p2] = (2.f/3.f)*g2;
    }
  }
  __syncthreads();
  if (tid < NC) atomicAdd(&imp_sum[tid], imp_loc[tid]);
}

__global__ void finalize_kernel(const float* __restrict__ imp_sum,
                                float* __restrict__ out)
{
  if (threadIdx.x == 0 && blockIdx.x == 0) {
    float lb = 0.f, ent = 0.f;
    for (int e = 0; e < NC; ++e) {
      float p = imp_sum[e] * (1.f/(float)N_TOK);
      float d = p - (1.f/(float)NC);
      lb += d*d;
      ent -= p * logf(fmaxf(p, 1e-8f));
    }
    out[OUT_MIXED]     = lb * (1.f/(float)NC);
    out[OUT_MIXED + 1] = ent;
  }
}

// ---------------------------------------------------------------------------
// bf16 conversion prep kernels
// ---------------------------------------------------------------------------
__global__ __launch_bounds__(256) void convert_x(const float* __restrict__ x,
                                                 unsigned short* __restrict__ xbf)
{
  const int g = blockIdx.x * 256 + threadIdx.x;   // 262144 threads, 8 elems each
  const float* src = x + (size_t)g * 8;
  unsigned short tmp[8];
#pragma unroll
  for (int j = 0; j < 8; ++j) tmp[j] = f2bf(src[j]);
  *(uint4*)(xbf + (size_t)g * 8) = *(const uint4*)tmp;
}

// W1s[e][ntile(128)][kblk(64)][n_lo(16)][k_lo(8)]
__global__ __launch_bounds__(256) void convert_w1(const float* __restrict__ W1,
                                                  unsigned short* __restrict__ W1s)
{
  const int g = blockIdx.x * 256 + threadIdx.x;   // 1,048,576 threads
  const int n_lo  = g & 15;
  const int kblk  = (g >> 4) & 63;
  const int ntile = (g >> 10) & 127;
  const int e     = g >> 17;
  const int n = ntile * 16 + n_lo;
  const float* src = W1 + ((size_t)e * DIM + kblk * 8) * HID + n;
  unsigned short tmp[8];
#pragma unroll
  for (int j = 0; j < 8; ++j) tmp[j] = f2bf(src[(size_t)j * HID]);
  unsigned short* dst = W1s + ((((size_t)e * 128 + ntile) * 64 + kblk) * 128 + n_lo * 8);
  *(uint4*)dst = *(const uint4*)tmp;
}

// W2s[e][ntile(32)][kblk(256)][n_lo(16)][k_lo(8)]
__global__ __launch_bounds__(256) void convert_w2(const float* __restrict__ W2,
                                                  unsigned short* __restrict__ W2s)
{
  const int g = blockIdx.x * 256 + threadIdx.x;   // 1,048,576 threads
  const int n_lo  = g & 15;
  const int kblk  = (g >> 4) & 255;
  const int ntile = (g >> 12) & 31;
  const int e     = g >> 17;
  const int n = ntile * 16 + n_lo;
  const float* src = W2 + ((size_t)e * HID + kblk * 8) * DIM + n;
  unsigned short tmp[8];
#pragma unroll
  for (int j = 0; j < 8; ++j) tmp[j] = f2bf(src[(size_t)j * DIM]);
  unsigned short* dst = W2s + ((((size_t)e * 32 + ntile) * 256 + kblk) * 128 + n_lo * 8);
  *(uint4*)dst = *(const uint4*)tmp;
}

// ---------------------------------------------------------------------------
// MFMA grouped MLP: block = (expert, 16-token tile), 4 waves.
// Phase1 per chunk c: H[16][256] = relu(X[16][512] @ W1e[:, c*256+...] + b1)
// Phase2: Y[16][512] += H @ W2e[c*256:(c+1)*256, :]
// A-operands from LDS (padded), B-operands one coalesced dwordx4 per MFMA.
// ---------------------------------------------------------------------------
__global__ __launch_bounds__(256) void moe_mlp_mfma(
    const unsigned short* __restrict__ xbf,
    const unsigned short* __restrict__ W1s,
    const unsigned short* __restrict__ W2s,
    const float* __restrict__ b1, const float* __restrict__ b2,
    const float* __restrict__ fixed_w,
    const int* __restrict__ counts, const int* __restrict__ tok_list,
    const float* __restrict__ wt_list, float* __restrict__ out)
{
  const int e    = blockIdx.x >> 8;
  const int tile = blockIdx.x & 255;
  const int cnt  = (e == 0) ? N_TOK : counts[e];
  const int start = tile * TM;
  if (start >= cnt) return;   // uniform per block

  __shared__ __align__(16) unsigned short xs[16 * XSP];  // 16640 B
  __shared__ __align__(16) unsigned short hs[16 * HSP];  //  8448 B
  __shared__ int   tok_s[TM];
  __shared__ float wt_s[TM];

  const int tid = threadIdx.x;
  if (tid < TM) {
    int idx = start + tid; int t = 0; float w = 0.f;
    if (idx < cnt) {
      if (e == 0) { t = idx; w = (1.f/3.f) * fixed_w[0]; }
      else        { t = tok_list[e*N_TOK + idx]; w = wt_list[e*N_TOK + idx]; }
    }
    tok_s[tid] = t; wt_s[tid] = w;
  }
  __syncthreads();

  // stage x tile as bf16: 16 rows x 512 cols, 16B chunks
  for (int i = tid; i < 16 * 64; i += 256) {
    const int m = i >> 6, cb = i & 63;
    *(uint4*)(xs + m * XSP + cb * 8) =
        *(const uint4*)(xbf + (size_t)tok_s[m] * DIM + cb * 8);
  }

  const int lane = tid & 63;
  const int w    = tid >> 6;
  const int n16  = lane & 15;
  const int q    = lane >> 4;

  const unsigned short* W1e = W1s + (size_t)e * 128 * 64 * 128;
  const unsigned short* W2e = W2s + (size_t)e * 32 * 256 * 128;

  f32x4 yacc[8];
#pragma unroll
  for (int t = 0; t < 8; ++t) yacc[t] = (f32x4){0.f, 0.f, 0.f, 0.f};

  __syncthreads();   // xs ready

  for (int c = 0; c < 8; ++c) {
    // ---- phase 1: 4 n-tiles per wave, K=512 (16 MFMA ksteps)
    f32x4 hacc[4];
#pragma unroll
    for (int t = 0; t < 4; ++t) hacc[t] = (f32x4){0.f, 0.f, 0.f, 0.f};
    const int nt_base = c * 16 + w * 4;
#pragma unroll 4
    for (int s = 0; s < 16; ++s) {
      const bf16x8 a = *(const bf16x8*)(xs + n16 * XSP + s * 32 + q * 8);
#pragma unroll
      for (int t = 0; t < 4; ++t) {
        const bf16x8 b = *(const bf16x8*)(
            W1e + (((size_t)(nt_base + t) * 64) + s * 4 + q) * 128 + n16 * 8);
        hacc[t] = __builtin_amdgcn_mfma_f32_16x16x32_bf16(a, b, hacc[t], 0, 0, 0);
      }
    }
    // bias + relu + store H chunk to LDS (C layout: row=q*4+reg, col=n16)
#pragma unroll
    for (int t = 0; t < 4; ++t) {
      const float bv = b1[e * HID + (nt_base + t) * 16 + n16];
      const int col = w * 64 + t * 16 + n16;
#pragma unroll
      for (int reg = 0; reg < 4; ++reg) {
        float v = fmaxf(hacc[t][reg] + bv, 0.f);
        hs[(q * 4 + reg) * HSP + col] = f2bf(v);
      }
    }
    __syncthreads();

    // ---- phase 2: 8 n-tiles per wave, K=256 (8 MFMA ksteps)
#pragma unroll 4
    for (int s = 0; s < 8; ++s) {
      const bf16x8 a = *(const bf16x8*)(hs + n16 * HSP + s * 32 + q * 8);
      const int kblk = c * 32 + s * 4 + q;
#pragma unroll
      for (int t = 0; t < 8; ++t) {
        const bf16x8 b = *(const bf16x8*)(
            W2e + (((size_t)(w * 8 + t) * 256) + kblk) * 128 + n16 * 8);
        yacc[t] = __builtin_amdgcn_mfma_f32_16x16x32_bf16(a, b, yacc[t], 0, 0, 0);
      }
    }
    __syncthreads();   // hs consumed before next chunk overwrites
  }

  // ---- epilogue: out[tok] += w * (y + b2)
#pragma unroll
  for (int t = 0; t < 8; ++t) {
    const int d = (w * 8 + t) * 16 + n16;
    const float b2v = b2[e * DIM + d];
#pragma unroll
    for (int reg = 0; reg < 4; ++reg) {
      const int m = q * 4 + reg;
      atomicAdd(&out[(size_t)tok_s[m] * DIM + d], wt_s[m] * (yacc[t][reg] + b2v));
    }
  }
}

// ---------------------------------------------------------------------------
// fp32 fallback (R1 kernel) — used only if ws_size < WS_REQ
// ---------------------------------------------------------------------------
__global__ __launch_bounds__(256) void moe_mlp_kernel(
    const float* __restrict__ x,
    const float* __restrict__ W1, const float* __restrict__ b1,
    const float* __restrict__ W2, const float* __restrict__ b2,
    const float* __restrict__ fixed_w,
    const int* __restrict__ counts, const int* __restrict__ tok_list,
    const float* __restrict__ wt_list, float* __restrict__ out)
{
  const int e    = blockIdx.x >> 8;
  const int tile = blockIdx.x & 255;
  const int cnt  = (e == 0) ? N_TOK : counts[e];
  const int start = tile * TM;
  if (start >= cnt) return;

  __shared__ float xs[DIM][TM+1];
  __shared__ float hs2[256][TM+1];
  __shared__ int   tok_s[TM];
  __shared__ float wt_s[TM];

  const int tid = threadIdx.x;
  if (tid < TM) {
    int idx = start + tid; int t = 0; float w = 0.f;
    if (idx < cnt) {
      if (e == 0) { t = idx; w = (1.f/3.f) * fixed_w[0]; }
      else        { t = tok_list[e*N_TOK + idx]; w = wt_list[e*N_TOK + idx]; }
    }
    tok_s[tid] = t; wt_s[tid] = w;
  }
  __syncthreads();

  for (int i = tid; i < TM*DIM; i += 256) {
    const int m = i >> 9, d = i & (DIM-1);
    xs[d][m] = x[(size_t)tok_s[m]*DIM + d];
  }

  const int r  = tid & 63;
  const int m0 = (tid >> 6) * 4;
  const float* W1e = W1 + (size_t)e * DIM * HID;
  const float* W2e = W2 + (size_t)e * HID * DIM;
  const float* b1e = b1 + e * HID;

  float yacc[4][8];
#pragma unroll
  for (int j = 0; j < 4; ++j)
#pragma unroll
    for (int i = 0; i < 8; ++i) yacc[j][i] = 0.f;

  __syncthreads();

  for (int c = 0; c < 8; ++c) {
    const int k0 = c * 256;
    float bv[4];
#pragma unroll
    for (int i = 0; i < 4; ++i) bv[i] = b1e[k0 + r + 64*i];
    float hacc[4][4];
#pragma unroll
    for (int j = 0; j < 4; ++j)
#pragma unroll
      for (int i = 0; i < 4; ++i) hacc[j][i] = bv[i];
#pragma unroll 2
    for (int d = 0; d < DIM; ++d) {
      float wv[4];
#pragma unroll
      for (int i = 0; i < 4; ++i) wv[i] = W1e[(size_t)d*HID + k0 + r + 64*i];
      float xv[4];
#pragma unroll
      for (int j = 0; j < 4; ++j) xv[j] = xs[d][m0+j];
#pragma unroll
      for (int j = 0; j < 4; ++j)
#pragma unroll
        for (int i = 0; i < 4; ++i) hacc[j][i] += xv[j]*wv[i];
    }
#pragma unroll
    for (int i = 0; i < 4; ++i)
#pragma unroll
      for (int j = 0; j < 4; ++j) hs2[r + 64*i][m0+j] = fmaxf(hacc[j][i], 0.f);
    __syncthreads();

#pragma unroll 2
    for (int k = 0; k < 256; ++k) {
      float wv2[8];
#pragma unroll
      for (int i = 0; i < 8; ++i) wv2[i] = W2e[(size_t)(k0+k)*DIM + r + 64*i];
      float hv[4];
#pragma unroll
      for (int j = 0; j < 4; ++j) hv[j] = hs2[k][m0+j];
#pragma unroll
      for (int j = 0; j < 4; ++j)
#pragma unroll
        for (int i = 0; i < 8; ++i) yacc[j][i] += hv[j]*wv2[i];
    }
    __syncthreads();
  }

#pragma unroll
  for (int i = 0; i < 8; ++i) {
    const int d = r + 64*i;
    const float b2v = b2[e*DIM + d];
#pragma unroll
    for (int j = 0; j < 4; ++j) {
      const int m = m0 + j;
      atomicAdd(&out[(size_t)tok_s[m]*DIM + d], wt_s[m]*(yacc[j][i] + b2v));
    }
  }
}

extern "C" void kernel_launch(void* const* d_in, const int* in_sizes, int n_in,
                              void* d_out, int out_size, void* d_ws, size_t ws_size,
                              hipStream_t stream)
{
  const float* x  = (const float*)d_in[0];
  const float* rW = (const float*)d_in[1];
  const float* rb = (const float*)d_in[2];
  const float* W1 = (const float*)d_in[3];
  const float* b1 = (const float*)d_in[4];
  const float* W2 = (const float*)d_in[5];
  const float* b2 = (const float*)d_in[6];
  const float* fw = (const float*)d_in[7];
  float* out = (float*)d_out;

  int*   counts   = (int*)d_ws;
  float* imp_sum  = (float*)((char*)d_ws + 32);
  int*   tok_list = (int*)((char*)d_ws + 64);
  float* wt_list  = (float*)((char*)d_ws + 64 + (size_t)NEXP*N_TOK*4);

  hipMemsetAsync(d_ws, 0, 64, stream);
  hipMemsetAsync(d_out, 0, (size_t)OUT_MIXED*4, stream);

  router_kernel<<<64, 256, 0, stream>>>(x, rW, rb, out, counts, imp_sum,
                                        tok_list, wt_list);
  finalize_kernel<<<1, 64, 0, stream>>>(imp_sum, out);

  if (ws_size >= WS_REQ) {
    unsigned short* xbf = (unsigned short*)((char*)d_ws + OFF_XBF);
    unsigned short* W1s = (unsigned short*)((char*)d_ws + OFF_W1S);
    unsigned short* W2s = (unsigned short*)((char*)d_ws + OFF_W2S);
    convert_x <<<1024, 256, 0, stream>>>(x, xbf);
    convert_w1<<<4096, 256, 0, stream>>>(W1, W1s);
    convert_w2<<<4096, 256, 0, stream>>>(W2, W2s);
    moe_mlp_mfma<<<NEXP*256, 256, 0, stream>>>(xbf, W1s, W2s, b1, b2, fw,
                                               counts, tok_list, wt_list, out);
  } else {
    moe_mlp_kernel<<<NEXP*256, 256, 0, stream>>>(x, W1, b1, W2, b2, fw,
                                                 counts, tok_list, wt_list, out);
  }
}

// Round 3
// 648.426 us; speedup vs baseline: 4.6979x; 1.1876x over previous
//
#include <hip/hip_runtime.h>
#include <math.h>

#define N_TOK 4096
#define DIM   512
#define HID   2048
#define NEXP  8
#define NC    7
#define OUT_MIXED (N_TOK*DIM)   // then [lb, ent], then sel_expert[N,2]
#define TM    32                // tokens per MLP block (M-tile)

typedef __attribute__((ext_vector_type(8))) short bf16x8;
typedef __attribute__((ext_vector_type(4))) float f32x4;

#define XSP 520   // xs row stride (elems): rows alias banks 2-way only (free)
#define HSP 264   // hs row stride (elems): same property

// ws layout:
//   [0,32)    int counts[8]
//   [32,64)   float imp_sum[8]
//   [64,  +8*4096*4)   int   tok_list[8][4096]
//   [...  +8*4096*4)   float wt_list[8][4096]
//   262208: xbf  [4096][512] bf16                    (4 MB)
//   : W1s  [8][128 ntile][64 kblk][16 n][8 k] bf16   (16 MB)
//   : W2s  [8][32 ntile][256 kblk][16 n][8 k] bf16   (16 MB)
#define OFF_XBF  262208ull
#define OFF_W1S  (OFF_XBF + 4194304ull)
#define OFF_W2S  (OFF_W1S + 16777216ull)
#define WS_REQ   (OFF_W2S + 16777216ull)

__device__ inline unsigned short f2bf(float f) {
  unsigned int u = __builtin_bit_cast(unsigned int, f);
  u = (u + 0x7fffu + ((u >> 16) & 1u)) >> 16;   // RNE
  return (unsigned short)u;
}

// ---------------------------------------------------------------------------
// Router (fp32 — sel_expert must be bit-exact). 256 blocks, 4 tokens/wave.
// ---------------------------------------------------------------------------
__global__ __launch_bounds__(256) void router_kernel(
    const float* __restrict__ x, const float* __restrict__ rW,
    const float* __restrict__ rb, float* __restrict__ out,
    int* __restrict__ counts, float* __restrict__ imp_sum,
    int* __restrict__ tok_list, float* __restrict__ wt_list)
{
  __shared__ float imp_loc[8];
  const int tid = threadIdx.x;
  if (tid < 8) imp_loc[tid] = 0.f;
  __syncthreads();
  const int wave = tid >> 6, lane = tid & 63;

  for (int it = 0; it < 4; ++it) {
    const int t = blockIdx.x * 16 + wave * 4 + it;
    float xv[8];
#pragma unroll
    for (int j = 0; j < 8; ++j) xv[j] = x[(size_t)t*DIM + lane + 64*j];
    float lg[NC];
#pragma unroll
    for (int e = 0; e < NC; ++e) {
      float s = 0.f;
#pragma unroll
      for (int j = 0; j < 8; ++j) s += xv[j] * rW[(lane + 64*j)*NC + e];
      lg[e] = s;
    }
#pragma unroll
    for (int e = 0; e < NC; ++e) {
      float s = lg[e];
#pragma unroll
      for (int off = 32; off > 0; off >>= 1) s += __shfl_xor(s, off, 64);
      lg[e] = s + rb[e];
    }
    int i1 = 0; float l1 = lg[0];
#pragma unroll
    for (int e = 1; e < NC; ++e) { if (lg[e] > l1) { l1 = lg[e]; i1 = e; } }
    int i2 = -1; float l2 = -3.4e38f;
#pragma unroll
    for (int e = 0; e < NC; ++e) { if (e != i1 && lg[e] > l2) { l2 = lg[e]; i2 = e; } }

    const float ed = expf(l2 - l1);
    const float g1 = 1.f/(1.f+ed), g2 = ed/(1.f+ed);

    float p[NC]; float ssum = 0.f;
#pragma unroll
    for (int e = 0; e < NC; ++e) { p[e] = expf(lg[e] - l1); ssum += p[e]; }
    const float inv = 1.f/ssum;

    if (lane == 0) {
#pragma unroll
      for (int e = 0; e < NC; ++e) atomicAdd(&imp_loc[e], p[e]*inv);
      out[OUT_MIXED + 2 + 2*t]     = (float)(i1 + 1);
      out[OUT_MIXED + 2 + 2*t + 1] = (float)(i2 + 1);
      const int e1 = i1 + 1, e2 = i2 + 1;
      int p1 = atomicAdd(&counts[e1], 1);
      tok_list[e1*N_TOK + p1] = t;
      wt_list [e1*N_TOK + p1] = (2.f/3.f)*g1;
      int p2 = atomicAdd(&counts[e2], 1);
      tok_list[e2*N_TOK + p2] = t;
      wt_list [e2*N_TOK + p2] = (2.f/3.f)*g2;
    }
  }
  __syncthreads();
  if (tid < NC) atomicAdd(&imp_sum[tid], imp_loc[tid]);
}

__global__ void finalize_kernel(const float* __restrict__ imp_sum,
                                float* __restrict__ out)
{
  if (threadIdx.x == 0 && blockIdx.x == 0) {
    float lb = 0.f, ent = 0.f;
    for (int e = 0; e < NC; ++e) {
      float p = imp_sum[e] * (1.f/(float)N_TOK);
      float d = p - (1.f/(float)NC);
      lb += d*d;
      ent -= p * logf(fmaxf(p, 1e-8f));
    }
    out[OUT_MIXED]     = lb * (1.f/(float)NC);
    out[OUT_MIXED + 1] = ent;
  }
}

// ---------------------------------------------------------------------------
// bf16 conversion prep
// ---------------------------------------------------------------------------
__global__ __launch_bounds__(256) void convert_x(const float* __restrict__ x,
                                                 unsigned short* __restrict__ xbf)
{
  const int g = blockIdx.x * 256 + threadIdx.x;
  const float* src = x + (size_t)g * 8;
  unsigned short tmp[8];
#pragma unroll
  for (int j = 0; j < 8; ++j) tmp[j] = f2bf(src[j]);
  *(uint4*)(xbf + (size_t)g * 8) = *(const uint4*)tmp;
}

// Coalesced LDS-transpose convert: W [8][K][Nm] fp32 -> Ws [8][Nm/16][K/8][16][8] bf16
// Tile: 32 k-rows x 256 n-cols. 128 blocks per expert for both W1 and W2.
__global__ __launch_bounds__(256) void convert_w(
    const float* __restrict__ W, unsigned int* __restrict__ Ws,
    int K, int Nm, int tiles_n)
{
  __shared__ unsigned short lds[32][264];
  const int tid = threadIdx.x;
  const int b  = blockIdx.x;
  const int e  = b >> 7;
  const int rm = b & 127;
  const int tk = rm / tiles_n;
  const int tn = rm - tk * tiles_n;

  const float* src = W + ((size_t)e * K + tk * 32) * Nm + tn * 256;
#pragma unroll
  for (int it = 0; it < 32; ++it) {
    const int i = it * 256 + tid;
    const int row = i >> 8, col = i & 255;
    lds[row][col] = f2bf(src[(size_t)row * Nm + col]);
  }
  __syncthreads();

  const int ntiles = Nm >> 4, kblks = K >> 3;
#pragma unroll
  for (int it = 0; it < 16; ++it) {
    const int uid   = it * 256 + tid;
    const int nt_l  = uid >> 8;
    const int r     = uid & 255;
    const int kb_l  = r >> 6;
    const int u     = r & 63;
    const int n_lo  = u >> 2;
    const int k_hf  = u & 3;
    const int d_l   = kb_l * 8 + k_hf * 2;
    const int h_l   = nt_l * 16 + n_lo;
    const unsigned int s0 = lds[d_l][h_l], s1 = lds[d_l + 1][h_l];
    const int nt_g = tn * 16 + nt_l;
    const int kb_g = tk * 4 + kb_l;
    const size_t frag = ((size_t)e * ntiles + nt_g) * kblks + kb_g;
    Ws[frag * 64 + n_lo * 4 + k_hf] = s0 | (s1 << 16);
  }
}

// ---------------------------------------------------------------------------
// MFMA grouped MLP: block = (expert, 32-token tile), 4 waves split N 4-way,
// each wave holds 2 A-fragments (M=32) -> 2 MFMA per B-load.
// ---------------------------------------------------------------------------
__global__ __launch_bounds__(256) void moe_mlp_mfma(
    const unsigned short* __restrict__ xbf,
    const unsigned short* __restrict__ W1s,
    const unsigned short* __restrict__ W2s,
    const float* __restrict__ b1, const float* __restrict__ b2,
    const float* __restrict__ fixed_w,
    const int* __restrict__ counts, const int* __restrict__ tok_list,
    const float* __restrict__ wt_list, float* __restrict__ out)
{
  const int e    = blockIdx.x >> 7;       // 128 tiles of 32 tokens per expert
  const int tile = blockIdx.x & 127;
  const int cnt  = (e == 0) ? N_TOK : counts[e];
  const int start = tile * TM;
  if (start >= cnt) return;   // uniform per block

  __shared__ __align__(16) unsigned short xs[32 * XSP];  // 33280 B
  __shared__ __align__(16) unsigned short hs[32 * HSP];  // 16896 B
  __shared__ int   tok_s[TM];
  __shared__ float wt_s[TM];

  const int tid = threadIdx.x;
  if (tid < TM) {
    int idx = start + tid; int t = 0; float w = 0.f;
    if (idx < cnt) {
      if (e == 0) { t = idx; w = (1.f/3.f) * fixed_w[0]; }
      else        { t = tok_list[e*N_TOK + idx]; w = wt_list[e*N_TOK + idx]; }
    }
    tok_s[tid] = t; wt_s[tid] = w;
  }
  __syncthreads();

  // stage x tile bf16: 32 rows x 64 16B-chunks
  for (int i = tid; i < 32 * 64; i += 256) {
    const int m = i >> 6, cb = i & 63;
    *(uint4*)(xs + m * XSP + cb * 8) =
        *(const uint4*)(xbf + (size_t)tok_s[m] * DIM + cb * 8);
  }

  const int lane = tid & 63;
  const int w    = tid >> 6;
  const int l15  = lane & 15;
  const int q    = lane >> 4;

  const unsigned short* W1e = W1s + (size_t)e * 128 * 64 * 128;
  const unsigned short* W2e = W2s + (size_t)e * 32 * 256 * 128;

  f32x4 yacc[2][8];
#pragma unroll
  for (int mi = 0; mi < 2; ++mi)
#pragma unroll
    for (int t = 0; t < 8; ++t) yacc[mi][t] = (f32x4){0.f, 0.f, 0.f, 0.f};

  __syncthreads();   // xs ready

  for (int c = 0; c < 8; ++c) {
    // ---- phase 1: wave owns 4 n-tiles of this 256-wide hidden chunk, K=512
    f32x4 hacc[2][4];
#pragma unroll
    for (int mi = 0; mi < 2; ++mi)
#pragma unroll
      for (int t = 0; t < 4; ++t) hacc[mi][t] = (f32x4){0.f, 0.f, 0.f, 0.f};
    const int nt_base = c * 16 + w * 4;
#pragma unroll 4
    for (int s = 0; s < 16; ++s) {
      const bf16x8 a0 = *(const bf16x8*)(xs + l15 * XSP + s * 32 + q * 8);
      const bf16x8 a1 = *(const bf16x8*)(xs + (16 + l15) * XSP + s * 32 + q * 8);
#pragma unroll
      for (int t = 0; t < 4; ++t) {
        const bf16x8 b = *(const bf16x8*)(
            W1e + (((size_t)(nt_base + t) * 64) + s * 4 + q) * 128 + l15 * 8);
        hacc[0][t] = __builtin_amdgcn_mfma_f32_16x16x32_bf16(a0, b, hacc[0][t], 0, 0, 0);
        hacc[1][t] = __builtin_amdgcn_mfma_f32_16x16x32_bf16(a1, b, hacc[1][t], 0, 0, 0);
      }
    }
    // bias + relu -> hs (C layout: row = q*4+reg [+16 for m1], col = n16)
#pragma unroll
    for (int t = 0; t < 4; ++t) {
      const float bv = b1[e * HID + (nt_base + t) * 16 + l15];
      const int col = w * 64 + t * 16 + l15;
#pragma unroll
      for (int reg = 0; reg < 4; ++reg) {
        hs[(q * 4 + reg) * HSP + col]        = f2bf(fmaxf(hacc[0][t][reg] + bv, 0.f));
        hs[(16 + q * 4 + reg) * HSP + col]   = f2bf(fmaxf(hacc[1][t][reg] + bv, 0.f));
      }
    }
    __syncthreads();

    // ---- phase 2: wave owns 8 output n-tiles (128 of 512 dims), K=256
#pragma unroll 2
    for (int s = 0; s < 8; ++s) {
      const bf16x8 a0 = *(const bf16x8*)(hs + l15 * HSP + s * 32 + q * 8);
      const bf16x8 a1 = *(const bf16x8*)(hs + (16 + l15) * HSP + s * 32 + q * 8);
      const int kblk = c * 32 + s * 4 + q;
#pragma unroll
      for (int t = 0; t < 8; ++t) {
        const bf16x8 b = *(const bf16x8*)(
            W2e + (((size_t)(w * 8 + t) * 256) + kblk) * 128 + l15 * 8);
        yacc[0][t] = __builtin_amdgcn_mfma_f32_16x16x32_bf16(a0, b, yacc[0][t], 0, 0, 0);
        yacc[1][t] = __builtin_amdgcn_mfma_f32_16x16x32_bf16(a1, b, yacc[1][t], 0, 0, 0);
      }
    }
    __syncthreads();   // hs consumed before next chunk overwrites
  }

  // ---- epilogue: out[tok] += w * (y + b2)
#pragma unroll
  for (int t = 0; t < 8; ++t) {
    const int d = (w * 8 + t) * 16 + l15;
    const float b2v = b2[e * DIM + d];
#pragma unroll
    for (int reg = 0; reg < 4; ++reg) {
      const int m0 = q * 4 + reg, m1 = 16 + q * 4 + reg;
      atomicAdd(&out[(size_t)tok_s[m0] * DIM + d], wt_s[m0] * (yacc[0][t][reg] + b2v));
      atomicAdd(&out[(size_t)tok_s[m1] * DIM + d], wt_s[m1] * (yacc[1][t][reg] + b2v));
    }
  }
}

// ---------------------------------------------------------------------------
// fp32 fallback — only if ws_size < WS_REQ
// ---------------------------------------------------------------------------
__global__ __launch_bounds__(256) void moe_mlp_kernel(
    const float* __restrict__ x,
    const float* __restrict__ W1, const float* __restrict__ b1,
    const float* __restrict__ W2, const float* __restrict__ b2,
    const float* __restrict__ fixed_w,
    const int* __restrict__ counts, const int* __restrict__ tok_list,
    const float* __restrict__ wt_list, float* __restrict__ out)
{
  const int e    = blockIdx.x >> 8;
  const int tile = blockIdx.x & 255;
  const int cnt  = (e == 0) ? N_TOK : counts[e];
  const int start = tile * 16;
  if (start >= cnt) return;

  __shared__ float xs[DIM][17];
  __shared__ float hs2[256][17];
  __shared__ int   tok_s[16];
  __shared__ float wt_s[16];

  const int tid = threadIdx.x;
  if (tid < 16) {
    int idx = start + tid; int t = 0; float w = 0.f;
    if (idx < cnt) {
      if (e == 0) { t = idx; w = (1.f/3.f) * fixed_w[0]; }
      else        { t = tok_list[e*N_TOK + idx]; w = wt_list[e*N_TOK + idx]; }
    }
    tok_s[tid] = t; wt_s[tid] = w;
  }
  __syncthreads();

  for (int i = tid; i < 16*DIM; i += 256) {
    const int m = i >> 9, d = i & (DIM-1);
    xs[d][m] = x[(size_t)tok_s[m]*DIM + d];
  }

  const int r  = tid & 63;
  const int m0 = (tid >> 6) * 4;
  const float* W1e = W1 + (size_t)e * DIM * HID;
  const float* W2e = W2 + (size_t)e * HID * DIM;
  const float* b1e = b1 + e * HID;

  float yacc[4][8];
#pragma unroll
  for (int j = 0; j < 4; ++j)
#pragma unroll
    for (int i = 0; i < 8; ++i) yacc[j][i] = 0.f;

  __syncthreads();

  for (int c = 0; c < 8; ++c) {
    const int k0 = c * 256;
    float bv[4];
#pragma unroll
    for (int i = 0; i < 4; ++i) bv[i] = b1e[k0 + r + 64*i];
    float hacc[4][4];
#pragma unroll
    for (int j = 0; j < 4; ++j)
#pragma unroll
      for (int i = 0; i < 4; ++i) hacc[j][i] = bv[i];
#pragma unroll 2
    for (int d = 0; d < DIM; ++d) {
      float wv[4];
#pragma unroll
      for (int i = 0; i < 4; ++i) wv[i] = W1e[(size_t)d*HID + k0 + r + 64*i];
      float xv[4];
#pragma unroll
      for (int j = 0; j < 4; ++j) xv[j] = xs[d][m0+j];
#pragma unroll
      for (int j = 0; j < 4; ++j)
#pragma unroll
        for (int i = 0; i < 4; ++i) hacc[j][i] += xv[j]*wv[i];
    }
#pragma unroll
    for (int i = 0; i < 4; ++i)
#pragma unroll
      for (int j = 0; j < 4; ++j) hs2[r + 64*i][m0+j] = fmaxf(hacc[j][i], 0.f);
    __syncthreads();

#pragma unroll 2
    for (int k = 0; k < 256; ++k) {
      float wv2[8];
#pragma unroll
      for (int i = 0; i < 8; ++i) wv2[i] = W2e[(size_t)(k0+k)*DIM + r + 64*i];
      float hv[4];
#pragma unroll
      for (int j = 0; j < 4; ++j) hv[j] = hs2[k][m0+j];
#pragma unroll
      for (int j = 0; j < 4; ++j)
#pragma unroll
        for (int i = 0; i < 8; ++i) yacc[j][i] += hv[j]*wv2[i];
    }
    __syncthreads();
  }

#pragma unroll
  for (int i = 0; i < 8; ++i) {
    const int d = r + 64*i;
    const float b2v = b2[e*DIM + d];
#pragma unroll
    for (int j = 0; j < 4; ++j) {
      const int m = m0 + j;
      atomicAdd(&out[(size_t)tok_s[m]*DIM + d], wt_s[m]*(yacc[j][i] + b2v));
    }
  }
}

extern "C" void kernel_launch(void* const* d_in, const int* in_sizes, int n_in,
                              void* d_out, int out_size, void* d_ws, size_t ws_size,
                              hipStream_t stream)
{
  const float* x  = (const float*)d_in[0];
  const float* rW = (const float*)d_in[1];
  const float* rb = (const float*)d_in[2];
  const float* W1 = (const float*)d_in[3];
  const float* b1 = (const float*)d_in[4];
  const float* W2 = (const float*)d_in[5];
  const float* b2 = (const float*)d_in[6];
  const float* fw = (const float*)d_in[7];
  float* out = (float*)d_out;

  int*   counts   = (int*)d_ws;
  float* imp_sum  = (float*)((char*)d_ws + 32);
  int*   tok_list = (int*)((char*)d_ws + 64);
  float* wt_list  = (float*)((char*)d_ws + 64 + (size_t)NEXP*N_TOK*4);

  hipMemsetAsync(d_ws, 0, 64, stream);
  hipMemsetAsync(d_out, 0, (size_t)OUT_MIXED*4, stream);

  router_kernel<<<256, 256, 0, stream>>>(x, rW, rb, out, counts, imp_sum,
                                         tok_list, wt_list);
  finalize_kernel<<<1, 64, 0, stream>>>(imp_sum, out);

  if (ws_size >= WS_REQ) {
    unsigned short* xbf = (unsigned short*)((char*)d_ws + OFF_XBF);
    unsigned int*   W1s = (unsigned int*)((char*)d_ws + OFF_W1S);
    unsigned int*   W2s = (unsigned int*)((char*)d_ws + OFF_W2S);
    convert_x<<<1024, 256, 0, stream>>>(x, xbf);
    convert_w<<<1024, 256, 0, stream>>>(W1, W1s, DIM, HID, 8);
    convert_w<<<1024, 256, 0, stream>>>(W2, W2s, HID, DIM, 2);
    moe_mlp_mfma<<<NEXP*128, 256, 0, stream>>>(xbf, (const unsigned short*)W1s,
                                               (const unsigned short*)W2s, b1, b2, fw,
                                               counts, tok_list, wt_list, out);
  } else {
    moe_mlp_kernel<<<NEXP*256, 256, 0, stream>>>(x, W1, b1, W2, b2, fw,
                                                 counts, tok_list, wt_list, out);
  }
}

// Round 4
// 272.000 us; speedup vs baseline: 11.1994x; 2.3839x over previous
//
#include <hip/hip_runtime.h>
#include <math.h>

#define N_TOK 4096
#define DIM   512
#define HID   2048
#define NEXP  8
#define NC    7
#define OUT_MIXED (N_TOK*DIM)   // then [lb, ent], then sel_expert[N,2]
#define TM    32                // tokens per MLP tile (M-tile)

typedef __attribute__((ext_vector_type(8))) short bf16x8;
typedef __attribute__((ext_vector_type(4))) float f32x4;

#define XSP 520   // xs row stride (elems): rows alias banks 2-way only (free)
#define HSP 264   // hs row stride (elems): same property

// ws layout:
//   [0,64)    (unused legacy)
//   [64,  +8*4096*4)   int   tok_list[8][4096]   ; expert-0 row reused:
//                        cpad[e*32]  = per-expert count, 128B apart
//   [...  +8*4096*4)   float wt_list[8][4096]    ; expert-0 row reused:
//                        ipad[e*32]  = per-expert importance sum, 128B apart
//   262208: xbf  [4096][512] bf16                    (4 MB)
//   : W1s  [8][128 ntile][64 kblk][16 n][8 k] bf16   (16 MB)
//   : W2s  [8][32 ntile][256 kblk][16 n][8 k] bf16   (16 MB)
#define OFF_XBF  262208ull
#define OFF_W1S  (OFF_XBF + 4194304ull)
#define OFF_W2S  (OFF_W1S + 16777216ull)
#define WS_REQ   (OFF_W2S + 16777216ull)

__device__ inline unsigned short f2bf(float f) {
  unsigned int u = __builtin_bit_cast(unsigned int, f);
  u = (u + 0x7fffu + ((u >> 16) & 1u)) >> 16;   // RNE
  return (unsigned short)u;
}

// ---------------------------------------------------------------------------
// Router (fp32 — sel_expert must be bit-exact). Block-local aggregation:
// LDS lists per expert, ONE padded global atomic per (block, expert).
// ---------------------------------------------------------------------------
__global__ __launch_bounds__(256) void router_kernel(
    const float* __restrict__ x, const float* __restrict__ rW,
    const float* __restrict__ rb, float* __restrict__ out,
    int* __restrict__ cpad, float* __restrict__ ipad,
    int* __restrict__ tok_list, float* __restrict__ wt_list)
{
  __shared__ float imp_loc[8];
  __shared__ int   cnt_loc[8];
  __shared__ int   ltok[8][32];
  __shared__ float lwt[8][32];
  __shared__ int   base_s[8];

  const int tid = threadIdx.x;
  if (tid < 8) { imp_loc[tid] = 0.f; cnt_loc[tid] = 0; }
  __syncthreads();
  const int wave = tid >> 6, lane = tid & 63;

  for (int it = 0; it < 4; ++it) {
    const int t = blockIdx.x * 16 + wave * 4 + it;
    float xv[8];
#pragma unroll
    for (int j = 0; j < 8; ++j) xv[j] = x[(size_t)t*DIM + lane + 64*j];
    float lg[NC];
#pragma unroll
    for (int e = 0; e < NC; ++e) {
      float s = 0.f;
#pragma unroll
      for (int j = 0; j < 8; ++j) s += xv[j] * rW[(lane + 64*j)*NC + e];
      lg[e] = s;
    }
#pragma unroll
    for (int e = 0; e < NC; ++e) {
      float s = lg[e];
#pragma unroll
      for (int off = 32; off > 0; off >>= 1) s += __shfl_xor(s, off, 64);
      lg[e] = s + rb[e];
    }
    int i1 = 0; float l1 = lg[0];
#pragma unroll
    for (int e = 1; e < NC; ++e) { if (lg[e] > l1) { l1 = lg[e]; i1 = e; } }
    int i2 = -1; float l2 = -3.4e38f;
#pragma unroll
    for (int e = 0; e < NC; ++e) { if (e != i1 && lg[e] > l2) { l2 = lg[e]; i2 = e; } }

    const float ed = expf(l2 - l1);
    const float g1 = 1.f/(1.f+ed), g2 = ed/(1.f+ed);

    float p[NC]; float ssum = 0.f;
#pragma unroll
    for (int e = 0; e < NC; ++e) { p[e] = expf(lg[e] - l1); ssum += p[e]; }
    const float inv = 1.f/ssum;

    if (lane == 0) {
#pragma unroll
      for (int e = 0; e < NC; ++e) atomicAdd(&imp_loc[e], p[e]*inv);
      out[OUT_MIXED + 2 + 2*t]     = (float)(i1 + 1);
      out[OUT_MIXED + 2 + 2*t + 1] = (float)(i2 + 1);
      const int e1 = i1 + 1, e2 = i2 + 1;
      int p1 = atomicAdd(&cnt_loc[e1], 1);
      ltok[e1][p1] = t;  lwt[e1][p1] = (2.f/3.f)*g1;
      int p2 = atomicAdd(&cnt_loc[e2], 1);
      ltok[e2][p2] = t;  lwt[e2][p2] = (2.f/3.f)*g2;
    }
  }
  __syncthreads();

  if (tid >= 1 && tid < 8)
    base_s[tid] = atomicAdd(&cpad[tid * 32], cnt_loc[tid]);
  if (tid < NC)
    atomicAdd(&ipad[(tid + 1) * 32], imp_loc[tid]);   // expert e=tid+1 slot
  __syncthreads();

  {
    const int e = tid >> 5, i = tid & 31;
    if (e >= 1 && i < cnt_loc[e]) {
      const int dst = e * N_TOK + base_s[e] + i;
      tok_list[dst] = ltok[e][i];
      wt_list [dst] = lwt[e][i];
    }
  }
}

__global__ void finalize_kernel(const float* __restrict__ ipad,
                                float* __restrict__ out)
{
  if (threadIdx.x == 0 && blockIdx.x == 0) {
    float lb = 0.f, ent = 0.f;
    for (int e = 0; e < NC; ++e) {
      float p = ipad[(e + 1) * 32] * (1.f/(float)N_TOK);
      float d = p - (1.f/(float)NC);
      lb += d*d;
      ent -= p * logf(fmaxf(p, 1e-8f));
    }
    out[OUT_MIXED]     = lb * (1.f/(float)NC);
    out[OUT_MIXED + 1] = ent;
  }
}

// ---------------------------------------------------------------------------
// bf16 conversion prep
// ---------------------------------------------------------------------------
__global__ __launch_bounds__(256) void convert_x(const float* __restrict__ x,
                                                 unsigned short* __restrict__ xbf)
{
  const int g = blockIdx.x * 256 + threadIdx.x;
  const float* src = x + (size_t)g * 8;
  unsigned short tmp[8];
#pragma unroll
  for (int j = 0; j < 8; ++j) tmp[j] = f2bf(src[j]);
  *(uint4*)(xbf + (size_t)g * 8) = *(const uint4*)tmp;
}

// Coalesced LDS-transpose convert: W [8][K][Nm] fp32 -> Ws [8][Nm/16][K/8][16][8] bf16
__global__ __launch_bounds__(256) void convert_w(
    const float* __restrict__ W, unsigned int* __restrict__ Ws,
    int K, int Nm, int tiles_n)
{
  __shared__ unsigned short lds[32][264];
  const int tid = threadIdx.x;
  const int b  = blockIdx.x;
  const int e  = b >> 7;
  const int rm = b & 127;
  const int tk = rm / tiles_n;
  const int tn = rm - tk * tiles_n;

  const float* src = W + ((size_t)e * K + tk * 32) * Nm + tn * 256;
#pragma unroll
  for (int it = 0; it < 32; ++it) {
    const int i = it * 256 + tid;
    const int row = i >> 8, col = i & 255;
    lds[row][col] = f2bf(src[(size_t)row * Nm + col]);
  }
  __syncthreads();

  const int ntiles = Nm >> 4, kblks = K >> 3;
#pragma unroll
  for (int it = 0; it < 16; ++it) {
    const int uid   = it * 256 + tid;
    const int nt_l  = uid >> 8;
    const int r     = uid & 255;
    const int kb_l  = r >> 6;
    const int u     = r & 63;
    const int n_lo  = u >> 2;
    const int k_hf  = u & 3;
    const int d_l   = kb_l * 8 + k_hf * 2;
    const int h_l   = nt_l * 16 + n_lo;
    const unsigned int s0 = lds[d_l][h_l], s1 = lds[d_l + 1][h_l];
    const int nt_g = tn * 16 + nt_l;
    const int kb_g = tk * 4 + kb_l;
    const size_t frag = ((size_t)e * ntiles + nt_g) * kblks + kb_g;
    Ws[frag * 64 + n_lo * 4 + k_hf] = s0 | (s1 << 16);
  }
}

// ---------------------------------------------------------------------------
// MFMA grouped MLP: block = (expert, 32-token tile, chunk-half), 8 waves.
// Each block processes 4 of the 8 hidden chunks; both halves atomicAdd into
// out (half 0 carries b2). Waves split N 8-way; 2 A-frags (M=32) per wave.
// ---------------------------------------------------------------------------
__global__ __launch_bounds__(512) void moe_mlp_mfma(
    const unsigned short* __restrict__ xbf,
    const unsigned short* __restrict__ W1s,
    const unsigned short* __restrict__ W2s,
    const float* __restrict__ b1, const float* __restrict__ b2,
    const float* __restrict__ fixed_w,
    const int* __restrict__ cpad, const int* __restrict__ tok_list,
    const float* __restrict__ wt_list, float* __restrict__ out)
{
  const int e    = blockIdx.x >> 8;       // [e(3b)][tile(7b)][half(1b)]
  const int rest = blockIdx.x & 255;
  const int tile = rest >> 1;
  const int half = rest & 1;
  const int cnt  = (e == 0) ? N_TOK : cpad[e * 32];
  const int start = tile * TM;
  if (start >= cnt) return;   // uniform per block

  __shared__ __align__(16) unsigned short xs[32 * XSP];  // 33280 B
  __shared__ __align__(16) unsigned short hs[32 * HSP];  // 16896 B
  __shared__ int   tok_s[TM];
  __shared__ float wt_s[TM];

  const int tid = threadIdx.x;
  if (tid < TM) {
    int idx = start + tid; int t = 0; float w = 0.f;
    if (idx < cnt) {
      if (e == 0) { t = idx; w = (1.f/3.f) * fixed_w[0]; }
      else        { t = tok_list[e*N_TOK + idx]; w = wt_list[e*N_TOK + idx]; }
    }
    tok_s[tid] = t; wt_s[tid] = w;
  }
  __syncthreads();

  // stage x tile bf16: 32 rows x 64 16B-chunks (512 threads -> 4 iters)
  for (int i = tid; i < 32 * 64; i += 512) {
    const int m = i >> 6, cb = i & 63;
    *(uint4*)(xs + m * XSP + cb * 8) =
        *(const uint4*)(xbf + (size_t)tok_s[m] * DIM + cb * 8);
  }

  const int lane = tid & 63;
  const int w    = tid >> 6;          // 0..7
  const int l15  = lane & 15;
  const int q    = lane >> 4;

  const unsigned short* W1e = W1s + (size_t)e * 128 * 64 * 128;
  const unsigned short* W2e = W2s + (size_t)e * 32 * 256 * 128;

  f32x4 yacc[2][4];
#pragma unroll
  for (int mi = 0; mi < 2; ++mi)
#pragma unroll
    for (int t = 0; t < 4; ++t) yacc[mi][t] = (f32x4){0.f, 0.f, 0.f, 0.f};

  __syncthreads();   // xs ready

  for (int c = half * 4; c < half * 4 + 4; ++c) {
    // ---- phase 1: wave owns 2 n-tiles of this 256-wide hidden chunk, K=512
    f32x4 hacc[2][2];
#pragma unroll
    for (int mi = 0; mi < 2; ++mi)
#pragma unroll
      for (int t = 0; t < 2; ++t) hacc[mi][t] = (f32x4){0.f, 0.f, 0.f, 0.f};
    const int nt_base = c * 16 + w * 2;
#pragma unroll 4
    for (int s = 0; s < 16; ++s) {
      const bf16x8 a0 = *(const bf16x8*)(xs + l15 * XSP + s * 32 + q * 8);
      const bf16x8 a1 = *(const bf16x8*)(xs + (16 + l15) * XSP + s * 32 + q * 8);
#pragma unroll
      for (int t = 0; t < 2; ++t) {
        const bf16x8 b = *(const bf16x8*)(
            W1e + (((size_t)(nt_base + t) * 64) + s * 4 + q) * 128 + l15 * 8);
        hacc[0][t] = __builtin_amdgcn_mfma_f32_16x16x32_bf16(a0, b, hacc[0][t], 0, 0, 0);
        hacc[1][t] = __builtin_amdgcn_mfma_f32_16x16x32_bf16(a1, b, hacc[1][t], 0, 0, 0);
      }
    }
    // bias + relu -> hs (C layout: row = q*4+reg [+16 for m1], col = local n)
#pragma unroll
    for (int t = 0; t < 2; ++t) {
      const float bv = b1[e * HID + (nt_base + t) * 16 + l15];
      const int col = w * 32 + t * 16 + l15;
#pragma unroll
      for (int reg = 0; reg < 4; ++reg) {
        hs[(q * 4 + reg) * HSP + col]      = f2bf(fmaxf(hacc[0][t][reg] + bv, 0.f));
        hs[(16 + q * 4 + reg) * HSP + col] = f2bf(fmaxf(hacc[1][t][reg] + bv, 0.f));
      }
    }
    __syncthreads();

    // ---- phase 2: wave owns 4 output n-tiles (64 of 512 dims), K=256
#pragma unroll 2
    for (int s = 0; s < 8; ++s) {
      const bf16x8 a0 = *(const bf16x8*)(hs + l15 * HSP + s * 32 + q * 8);
      const bf16x8 a1 = *(const bf16x8*)(hs + (16 + l15) * HSP + s * 32 + q * 8);
      const int kblk = c * 32 + s * 4 + q;
#pragma unroll
      for (int t = 0; t < 4; ++t) {
        const bf16x8 b = *(const bf16x8*)(
            W2e + (((size_t)(w * 4 + t) * 256) + kblk) * 128 + l15 * 8);
        yacc[0][t] = __builtin_amdgcn_mfma_f32_16x16x32_bf16(a0, b, yacc[0][t], 0, 0, 0);
        yacc[1][t] = __builtin_amdgcn_mfma_f32_16x16x32_bf16(a1, b, yacc[1][t], 0, 0, 0);
      }
    }
    __syncthreads();   // hs consumed before next chunk overwrites
  }

  // ---- epilogue: out[tok] += wt * (y_half + b2*(half==0))
#pragma unroll
  for (int t = 0; t < 4; ++t) {
    const int d = (w * 4 + t) * 16 + l15;
    const float b2v = half ? 0.f : b2[e * DIM + d];
#pragma unroll
    for (int reg = 0; reg < 4; ++reg) {
      const int m0 = q * 4 + reg, m1 = 16 + q * 4 + reg;
      atomicAdd(&out[(size_t)tok_s[m0] * DIM + d], wt_s[m0] * (yacc[0][t][reg] + b2v));
      atomicAdd(&out[(size_t)tok_s[m1] * DIM + d], wt_s[m1] * (yacc[1][t][reg] + b2v));
    }
  }
}

// ---------------------------------------------------------------------------
// fp32 fallback — only if ws_size < WS_REQ
// ---------------------------------------------------------------------------
__global__ __launch_bounds__(256) void moe_mlp_kernel(
    const float* __restrict__ x,
    const float* __restrict__ W1, const float* __restrict__ b1,
    const float* __restrict__ W2, const float* __restrict__ b2,
    const float* __restrict__ fixed_w,
    const int* __restrict__ cpad, const int* __restrict__ tok_list,
    const float* __restrict__ wt_list, float* __restrict__ out)
{
  const int e    = blockIdx.x >> 8;
  const int tile = blockIdx.x & 255;
  const int cnt  = (e == 0) ? N_TOK : cpad[e * 32];
  const int start = tile * 16;
  if (start >= cnt) return;

  __shared__ float xs[DIM][17];
  __shared__ float hs2[256][17];
  __shared__ int   tok_s[16];
  __shared__ float wt_s[16];

  const int tid = threadIdx.x;
  if (tid < 16) {
    int idx = start + tid; int t = 0; float w = 0.f;
    if (idx < cnt) {
      if (e == 0) { t = idx; w = (1.f/3.f) * fixed_w[0]; }
      else        { t = tok_list[e*N_TOK + idx]; w = wt_list[e*N_TOK + idx]; }
    }
    tok_s[tid] = t; wt_s[tid] = w;
  }
  __syncthreads();

  for (int i = tid; i < 16*DIM; i += 256) {
    const int m = i >> 9, d = i & (DIM-1);
    xs[d][m] = x[(size_t)tok_s[m]*DIM + d];
  }

  const int r  = tid & 63;
  const int m0 = (tid >> 6) * 4;
  const float* W1e = W1 + (size_t)e * DIM * HID;
  const float* W2e = W2 + (size_t)e * HID * DIM;
  const float* b1e = b1 + e * HID;

  float yacc[4][8];
#pragma unroll
  for (int j = 0; j < 4; ++j)
#pragma unroll
    for (int i = 0; i < 8; ++i) yacc[j][i] = 0.f;

  __syncthreads();

  for (int c = 0; c < 8; ++c) {
    const int k0 = c * 256;
    float bv[4];
#pragma unroll
    for (int i = 0; i < 4; ++i) bv[i] = b1e[k0 + r + 64*i];
    float hacc[4][4];
#pragma unroll
    for (int j = 0; j < 4; ++j)
#pragma unroll
      for (int i = 0; i < 4; ++i) hacc[j][i] = bv[i];
#pragma unroll 2
    for (int d = 0; d < DIM; ++d) {
      float wv[4];
#pragma unroll
      for (int i = 0; i < 4; ++i) wv[i] = W1e[(size_t)d*HID + k0 + r + 64*i];
      float xv[4];
#pragma unroll
      for (int j = 0; j < 4; ++j) xv[j] = xs[d][m0+j];
#pragma unroll
      for (int j = 0; j < 4; ++j)
#pragma unroll
        for (int i = 0; i < 4; ++i) hacc[j][i] += xv[j]*wv[i];
    }
#pragma unroll
    for (int i = 0; i < 4; ++i)
#pragma unroll
      for (int j = 0; j < 4; ++j) hs2[r + 64*i][m0+j] = fmaxf(hacc[j][i], 0.f);
    __syncthreads();

#pragma unroll 2
    for (int k = 0; k < 256; ++k) {
      float wv2[8];
#pragma unroll
      for (int i = 0; i < 8; ++i) wv2[i] = W2e[(size_t)(k0+k)*DIM + r + 64*i];
      float hv[4];
#pragma unroll
      for (int j = 0; j < 4; ++j) hv[j] = hs2[k][m0+j];
#pragma unroll
      for (int j = 0; j < 4; ++j)
#pragma unroll
        for (int i = 0; i < 8; ++i) yacc[j][i] += hv[j]*wv2[i];
    }
    __syncthreads();
  }

#pragma unroll
  for (int i = 0; i < 8; ++i) {
    const int d = r + 64*i;
    const float b2v = b2[e*DIM + d];
#pragma unroll
    for (int j = 0; j < 4; ++j) {
      const int m = m0 + j;
      atomicAdd(&out[(size_t)tok_s[m]*DIM + d], wt_s[m]*(yacc[j][i] + b2v));
    }
  }
}

extern "C" void kernel_launch(void* const* d_in, const int* in_sizes, int n_in,
                              void* d_out, int out_size, void* d_ws, size_t ws_size,
                              hipStream_t stream)
{
  const float* x  = (const float*)d_in[0];
  const float* rW = (const float*)d_in[1];
  const float* rb = (const float*)d_in[2];
  const float* W1 = (const float*)d_in[3];
  const float* b1 = (const float*)d_in[4];
  const float* W2 = (const float*)d_in[5];
  const float* b2 = (const float*)d_in[6];
  const float* fw = (const float*)d_in[7];
  float* out = (float*)d_out;

  int*   tok_list = (int*)((char*)d_ws + 64);
  float* wt_list  = (float*)((char*)d_ws + 64 + (size_t)NEXP*N_TOK*4);
  int*   cpad     = tok_list;          // expert-0 row unused: counters, 128B apart
  float* ipad     = wt_list;           // expert-0 row unused: importance sums

  hipMemsetAsync(cpad, 0, 1024, stream);
  hipMemsetAsync(ipad, 0, 1024, stream);
  hipMemsetAsync(d_out, 0, (size_t)OUT_MIXED*4, stream);

  router_kernel<<<256, 256, 0, stream>>>(x, rW, rb, out, cpad, ipad,
                                         tok_list, wt_list);
  finalize_kernel<<<1, 64, 0, stream>>>(ipad, out);

  if (ws_size >= WS_REQ) {
    unsigned short* xbf = (unsigned short*)((char*)d_ws + OFF_XBF);
    unsigned int*   W1s = (unsigned int*)((char*)d_ws + OFF_W1S);
    unsigned int*   W2s = (unsigned int*)((char*)d_ws + OFF_W2S);
    convert_x<<<1024, 256, 0, stream>>>(x, xbf);
    convert_w<<<1024, 256, 0, stream>>>(W1, W1s, DIM, HID, 8);
    convert_w<<<1024, 256, 0, stream>>>(W2, W2s, HID, DIM, 2);
    moe_mlp_mfma<<<NEXP*256, 512, 0, stream>>>(xbf, (const unsigned short*)W1s,
                                               (const unsigned short*)W2s, b1, b2, fw,
                                               cpad, tok_list, wt_list, out);
  } else {
    moe_mlp_kernel<<<NEXP*256, 256, 0, stream>>>(x, W1, b1, W2, b2, fw,
                                                 cpad, tok_list, wt_list, out);
  }
}